// Round 9
// baseline (321.075 us; speedup 1.0000x reference)
//
#include <hip/hip_runtime.h>
#include <hip/hip_fp16.h>
#include <stdint.h>

#define CBP_D 8192
#define CBP_C 512
#define CBP_W 512
#define ROWS 64          // rows staged per block; lane covers 4 rows
#define NTHREADS 1024    // 16 waves
#define NSPLIT 4         // 64 row-blocks x 4 = 256 blocks = 1/CU
#define NCAP 72          // fixed pair-list capacity per d

// LDS layout (bytes): x2 rows 0..512 (513*128, row 512 = zeros), then x1 rows 0..511
#define X1OFF 65664
#define PADW  (512u << 17)   // pad pair word: j=512 (zero row), i=0

typedef float vf4 __attribute__((ext_vector_type(4)));   // native vec for nontemporal store

// ================= precompute (single fused kernel) =================
// 128 blocks x 512 threads. Each block independently rebuilds the h2 bucket
// tables in LDS (redundant, concurrent), then builds pair lists for its
// 64 d's with 8 threads per d. Deterministic: bucket order via rank, i-major.
__global__ __launch_bounds__(512, 2)
void pB_fill(const int* __restrict__ h1, const int* __restrict__ h2,
             int* __restrict__ cnt, uint32_t* __restrict__ pairs) {
    __shared__ int sc[CBP_D];       // 32 KB: h2 histogram (counts per bucket)
    __shared__ int sb[CBP_D];       // 32 KB: bucket start offsets
    __shared__ int ssum[512];
    __shared__ short sbk[CBP_C];    // bucket-ordered j list
    __shared__ int sh1[CBP_C];
    __shared__ int sh2[CBP_C];
    __shared__ int pc[64][8];       // per-(d, part) pair counts
    __shared__ int rawt[64];        // per-d totals
    int tid = threadIdx.x;          // 512

    for (int k = tid; k < CBP_D; k += 512) sc[k] = 0;
    sh1[tid] = h1[tid];
    sh2[tid] = h2[tid];
    __syncthreads();
    atomicAdd(&sc[sh2[tid]], 1);    // LDS histogram; counts order-independent
    __syncthreads();
    // exclusive scan of sc -> sb (512 threads x 16 bins)
    int base = tid * 16;
    int loc[16]; int s = 0;
#pragma unroll
    for (int k = 0; k < 16; ++k) { loc[k] = sc[base + k]; s += loc[k]; }
    ssum[tid] = s;
    __syncthreads();
    int acc = s;
    for (int off = 1; off < 512; off <<= 1) {
        int add = (tid >= off) ? ssum[tid - off] : 0;
        __syncthreads();
        acc += add; ssum[tid] = acc;
        __syncthreads();
    }
    int excl = acc - s;
#pragma unroll
    for (int k = 0; k < 16; ++k) { sb[base + k] = excl; excl += loc[k]; }
    __syncthreads();
    // deterministic bucket fill: rank of j among equal h2 values
    {
        int h = sh2[tid]; int r = 0;
        for (int j2 = 0; j2 < tid; ++j2) r += (sh2[j2] == h);
        sbk[sb[h] + r] = (short)tid;
    }
    __syncthreads();

    // ---- pair-list build: 8 threads per d, 64 d's per block ----
    int dl = tid >> 3, p = tid & 7;
    int d = blockIdx.x * 64 + dl;
    int i0 = p << 6;                 // 64 i's per part
    int cp = 0;
#pragma unroll 4
    for (int i = i0; i < i0 + 64; ++i) cp += sc[(d - sh1[i]) & (CBP_D - 1)];
    pc[dl][p] = cp;
    __syncthreads();
    int off = 0, tot = 0;
#pragma unroll
    for (int p2 = 0; p2 < 8; ++p2) { int v = pc[dl][p2]; off += (p2 < p) ? v : 0; tot += v; }
    uint32_t* pd = pairs + (size_t)d * NCAP;
    int pos = off;
    for (int i = i0; i < i0 + 64; ++i) {
        int t = (d - sh1[i]) & (CBP_D - 1);
        int n = sc[t];
        if (n) {
            int bo = sb[t];
            uint32_t iw = (uint32_t)(i << 7);
            for (int k = 0; k < n; ++k)
                pd[pos++] = iw | ((uint32_t)sbk[bo + k] << 17);
        }
    }
    if (p == 0) rawt[dl] = tot;
    __syncthreads();
    int q = dl & ~3;
    int qmax = max(max(rawt[q], rawt[q + 1]), max(rawt[q + 2], rawt[q + 3]));
    qmax = (qmax + 3) & ~3;
    for (int pos2 = tot + p; pos2 < qmax; pos2 += 8) pd[pos2] = PADW;
    if (p == 0) cnt[d] = qmax;
}

// ================= main =================

// Quarter g (lane>>4) owns d = quadbase+g; lane l (lane&15) covers rows 4l..4l+3.
#define PROC(P) { \
    uint32_t p_ = (P); \
    uint32_t aB_ = (p_ & 0x1FF80u) + baseA; \
    uint32_t bB_ = ((p_ >> 10) & 0x1FF80u) | baseB; \
    uint2 ra_ = *(const uint2*)(xsh + aB_); \
    uint2 rb_ = *(const uint2*)(xsh + bB_); \
    a01 = __hfma2(*(const __half2*)&ra_.x, *(const __half2*)&rb_.x, a01); \
    a23 = __hfma2(*(const __half2*)&ra_.y, *(const __half2*)&rb_.y, a23); }

// Process one quad (4 consecutive d); result vf4 (this lane's row, 4 d) in DEST.
// Maintains the cross-quad pipeline regs nmax_cur/pp_cur.
#define QUAD(K, DEST) { \
    int q_ = (qq << 2) + (K); \
    int quadbase_ = dbase + (q_ << 2); \
    int nmax_ = nmax_cur; \
    uint4 cur_ = pp_cur; \
    int nq_ = (q_ + 1 < 32) ? q_ + 1 : 31; \
    int nmax_n_ = __builtin_amdgcn_readfirstlane(cnt[dbase + (nq_ << 2)]); \
    uint4 pp_n_ = *(const uint4*)(pairs + (size_t)(dbase + (nq_ << 2) + g4) * NCAP); \
    const uint4* pl4_ = (const uint4*)(pairs + (size_t)(quadbase_ + g4) * NCAP); \
    float ac0 = 0.f, ac1 = 0.f, ac2 = 0.f, ac3 = 0.f; \
    int nb_ = nmax_ >> 2; \
    int t4_ = 0; \
    while (t4_ < nb_) { \
        __half2 a01 = __floats2half2_rn(0.f, 0.f); \
        __half2 a23 = __floats2half2_rn(0.f, 0.f); \
        int ce_ = (t4_ + 4 < nb_) ? t4_ + 4 : nb_; \
        for (; t4_ < ce_; ++t4_) { \
            uint4 c_ = cur_; \
            int nxt_ = (t4_ + 1 < nb_) ? t4_ + 1 : t4_; \
            cur_ = pl4_[nxt_]; \
            PROC(c_.x); PROC(c_.y); PROC(c_.z); PROC(c_.w); \
        } \
        float2 u_ = __half22float2(a01); ac0 += u_.x; ac1 += u_.y; \
        float2 v_ = __half22float2(a23); ac2 += v_.x; ac3 += v_.y; \
    } \
    nmax_cur = nmax_n_; pp_cur = pp_n_; \
    float s0_ = __shfl_xor(ac0, 16, 64), s1_ = __shfl_xor(ac1, 16, 64); \
    float s2_ = __shfl_xor(ac2, 16, 64), s3_ = __shfl_xor(ac3, 16, 64); \
    bool ge1_ = (g4 & 1) == 0; \
    float n0_ = ge1_ ? ac0 : s1_, n1_ = ge1_ ? s0_ : ac1; \
    float n2_ = ge1_ ? ac2 : s3_, n3_ = ge1_ ? s2_ : ac3; \
    s0_ = __shfl_xor(n0_, 32, 64); s1_ = __shfl_xor(n1_, 32, 64); \
    s2_ = __shfl_xor(n2_, 32, 64); s3_ = __shfl_xor(n3_, 32, 64); \
    bool ge2_ = (g4 & 2) == 0; \
    DEST[0] = ge2_ ? n0_ : s2_; DEST[1] = ge2_ ? n1_ : s3_; \
    DEST[2] = ge2_ ? s0_ : n2_; DEST[3] = ge2_ ? s1_ : n3_; }

__global__ __launch_bounds__(NTHREADS, 4)
void k_main(const float* __restrict__ b1, const float* __restrict__ b2,
            const float* __restrict__ s1, const float* __restrict__ s2,
            const int* __restrict__ cnt, const uint32_t* __restrict__ pairs,
            float* __restrict__ out) {
    __shared__ __align__(16) char xsh[131200];   // x2 (513 rows incl zero) + x1 (512)
    int bx = blockIdx.x;                   // 0..63 row-block
    int gy = blockIdx.y;                   // 0..3
    int r_base = bx * ROWS;
    int b = r_base >> 9;
    int w0 = r_base & (CBP_W - 1);
    int tid = threadIdx.x;

    // stage sign-folded f16, transposed [c][r]; x2 at 0, x1 at X1OFF
    for (int u = tid; u < CBP_C * 8; u += NTHREADS) {
        int c = u >> 3;
        int r8 = (u & 7) << 3;
        size_t g = ((size_t)(b * CBP_C + c)) * CBP_W + w0 + r8;
        float4 u0 = *(const float4*)(b1 + g), u1 = *(const float4*)(b1 + g + 4);
        float4 v0 = *(const float4*)(b2 + g), v1 = *(const float4*)(b2 + g + 4);
        float sa = s1[c], sb = s2[c];
        union { __half2 h2[4]; uint4 q; } A, Bv;
        A.h2[0] = __floats2half2_rn(u0.x * sa, u0.y * sa);
        A.h2[1] = __floats2half2_rn(u0.z * sa, u0.w * sa);
        A.h2[2] = __floats2half2_rn(u1.x * sa, u1.y * sa);
        A.h2[3] = __floats2half2_rn(u1.z * sa, u1.w * sa);
        Bv.h2[0] = __floats2half2_rn(v0.x * sb, v0.y * sb);
        Bv.h2[1] = __floats2half2_rn(v0.z * sb, v0.w * sb);
        Bv.h2[2] = __floats2half2_rn(v1.x * sb, v1.y * sb);
        Bv.h2[3] = __floats2half2_rn(v1.z * sb, v1.w * sb);
        *(uint4*)(xsh + X1OFF + (c << 7) + (r8 << 1)) = A.q;
        *(uint4*)(xsh + (c << 7) + (r8 << 1)) = Bv.q;
    }
    if (tid < 8) *(uint4*)(xsh + 65536 + tid * 16) = make_uint4(0, 0, 0, 0);
    __syncthreads();

    int wv = tid >> 6;                     // 0..15
    int lane = tid & 63;
    int g4 = lane >> 4;                    // quarter: d within quad
    int l = lane & 15;                     // rows 4l..4l+3
    uint32_t baseA = (uint32_t)(X1OFF + (l << 3));
    uint32_t baseB = (uint32_t)(l << 3);
    int dbase = gy * (CBP_D / NSPLIT) + wv * 128;   // wave owns 128 contiguous d's

    // cross-quad pipeline: preloaded count + first uint4 of the upcoming quad
    int nmax_cur = __builtin_amdgcn_readfirstlane(cnt[dbase]);
    uint4 pp_cur = *(const uint4*)(pairs + (size_t)(dbase + g4) * NCAP);

    // lane stores row r_base + 4l + g4, 16 consecutive d (64 B) per burst
    float* obase = out + (size_t)(r_base + (l << 2) + g4) * CBP_D + dbase;

    for (int qq = 0; qq < 8; ++qq) {
        vf4 B0, B1, B2, B3;
        QUAD(0, B0); QUAD(1, B1); QUAD(2, B2); QUAD(3, B3);
        float* o_ = obase + (qq << 4);
        __builtin_nontemporal_store(B0, (vf4*)(o_));
        __builtin_nontemporal_store(B1, (vf4*)(o_ + 4));
        __builtin_nontemporal_store(B2, (vf4*)(o_ + 8));
        __builtin_nontemporal_store(B3, (vf4*)(o_ + 12));
    }
}

// ================= launch =================

extern "C" void kernel_launch(void* const* d_in, const int* in_sizes, int n_in,
                              void* d_out, int out_size, void* d_ws, size_t ws_size,
                              hipStream_t stream) {
    const float* b1 = (const float*)d_in[0];
    const float* b2 = (const float*)d_in[1];
    const int*   h1 = (const int*)d_in[2];
    const float* s1 = (const float*)d_in[3];
    const int*   h2 = (const int*)d_in[4];
    const float* s2 = (const float*)d_in[5];
    float* out = (float*)d_out;

    int* cnt = (int*)d_ws;                            // 8192 (+8 pad)
    uint32_t* pairs = (uint32_t*)(cnt + 8192 + 8);    // 8192*NCAP u32 (~2.36 MB)

    pB_fill<<<128, 512, 0, stream>>>(h1, h2, cnt, pairs);

    dim3 g(CBP_W * 8 / ROWS, NSPLIT);     // (64, 4)
    k_main<<<g, NTHREADS, 0, stream>>>(b1, b2, s1, s2, cnt, pairs, out);
}

// Round 10
// 152.320 us; speedup vs baseline: 2.1079x; 2.1079x over previous
//
#include <hip/hip_runtime.h>
#include <hip/hip_fp16.h>
#include <stdint.h>

#define CBP_D 8192
#define CBP_C 512
#define CBP_W 512
#define ROWS 64          // rows staged per block; lane covers 4 rows
#define NTHREADS 1024    // 16 waves
#define NSPLIT 4         // 64 row-blocks x 4 = 256 blocks = 1/CU
#define NCAP 72          // fixed pair-list capacity per d

// LDS layout (bytes): x2 rows 0..512 (513*128, row 512 = zeros), then x1 rows 0..511
#define X1OFF 65664
#define PADW  (512u << 17)   // pad pair word: j=512 (zero row), i=0

// ================= precompute (single fused kernel) =================
// 128 blocks x 512 threads. Each block independently rebuilds the h2 bucket
// tables in LDS (redundant, concurrent), then builds pair lists for its
// 64 d's with 8 threads per d. Deterministic: bucket order via rank, i-major.
__global__ __launch_bounds__(512, 2)
void pB_fill(const int* __restrict__ h1, const int* __restrict__ h2,
             int* __restrict__ cnt, uint32_t* __restrict__ pairs) {
    __shared__ int sc[CBP_D];       // 32 KB: h2 histogram (counts per bucket)
    __shared__ int sb[CBP_D];       // 32 KB: bucket start offsets
    __shared__ int ssum[512];
    __shared__ short sbk[CBP_C];    // bucket-ordered j list
    __shared__ int sh1[CBP_C];
    __shared__ int sh2[CBP_C];
    __shared__ int pc[64][8];       // per-(d, part) pair counts
    __shared__ int rawt[64];        // per-d totals
    int tid = threadIdx.x;          // 512

    for (int k = tid; k < CBP_D; k += 512) sc[k] = 0;
    sh1[tid] = h1[tid];
    sh2[tid] = h2[tid];
    __syncthreads();
    atomicAdd(&sc[sh2[tid]], 1);    // LDS histogram; counts order-independent
    __syncthreads();
    // exclusive scan of sc -> sb (512 threads x 16 bins)
    int base = tid * 16;
    int loc[16]; int s = 0;
#pragma unroll
    for (int k = 0; k < 16; ++k) { loc[k] = sc[base + k]; s += loc[k]; }
    ssum[tid] = s;
    __syncthreads();
    int acc = s;
    for (int off = 1; off < 512; off <<= 1) {
        int add = (tid >= off) ? ssum[tid - off] : 0;
        __syncthreads();
        acc += add; ssum[tid] = acc;
        __syncthreads();
    }
    int excl = acc - s;
#pragma unroll
    for (int k = 0; k < 16; ++k) { sb[base + k] = excl; excl += loc[k]; }
    __syncthreads();
    // deterministic bucket fill: rank of j among equal h2 values
    {
        int h = sh2[tid]; int r = 0;
        for (int j2 = 0; j2 < tid; ++j2) r += (sh2[j2] == h);
        sbk[sb[h] + r] = (short)tid;
    }
    __syncthreads();

    // ---- pair-list build: 8 threads per d, 64 d's per block ----
    int dl = tid >> 3, p = tid & 7;
    int d = blockIdx.x * 64 + dl;
    int i0 = p << 6;                 // 64 i's per part
    int cp = 0;
#pragma unroll 4
    for (int i = i0; i < i0 + 64; ++i) cp += sc[(d - sh1[i]) & (CBP_D - 1)];
    pc[dl][p] = cp;
    __syncthreads();
    int off = 0, tot = 0;
#pragma unroll
    for (int p2 = 0; p2 < 8; ++p2) { int v = pc[dl][p2]; off += (p2 < p) ? v : 0; tot += v; }
    uint32_t* pd = pairs + (size_t)d * NCAP;
    int pos = off;
    for (int i = i0; i < i0 + 64; ++i) {
        int t = (d - sh1[i]) & (CBP_D - 1);
        int n = sc[t];
        if (n) {
            int bo = sb[t];
            uint32_t iw = (uint32_t)(i << 7);
            for (int k = 0; k < n; ++k)
                pd[pos++] = iw | ((uint32_t)sbk[bo + k] << 17);
        }
    }
    if (p == 0) rawt[dl] = tot;
    __syncthreads();
    int q = dl & ~3;
    int qmax = max(max(rawt[q], rawt[q + 1]), max(rawt[q + 2], rawt[q + 3]));
    qmax = (qmax + 3) & ~3;
    for (int pos2 = tot + p; pos2 < qmax; pos2 += 8) pd[pos2] = PADW;
    if (p == 0) cnt[d] = qmax;
}

// ================= main =================

// Quarter g (lane>>4) owns d = quadbase+g; lane l (lane&15) covers rows 4l..4l+3.
#define PROC(P) { \
    uint32_t p_ = (P); \
    uint32_t aB_ = (p_ & 0x1FF80u) + baseA; \
    uint32_t bB_ = ((p_ >> 10) & 0x1FF80u) | baseB; \
    uint2 ra_ = *(const uint2*)(xsh + aB_); \
    uint2 rb_ = *(const uint2*)(xsh + bB_); \
    a01 = __hfma2(*(const __half2*)&ra_.x, *(const __half2*)&rb_.x, a01); \
    a23 = __hfma2(*(const __half2*)&ra_.y, *(const __half2*)&rb_.y, a23); }

// Process one quad (4 consecutive d); result float4 (this lane's row, 4 d) in DEST.
// Maintains the cross-quad pipeline regs nmax_cur/pp_cur.
#define QUAD(K, DEST) { \
    int q_ = (qq << 2) + (K); \
    int quadbase_ = dbase + (q_ << 2); \
    int nmax_ = nmax_cur; \
    uint4 cur_ = pp_cur; \
    int nq_ = (q_ + 1 < 32) ? q_ + 1 : 31; \
    int nmax_n_ = __builtin_amdgcn_readfirstlane(cnt[dbase + (nq_ << 2)]); \
    uint4 pp_n_ = *(const uint4*)(pairs + (size_t)(dbase + (nq_ << 2) + g4) * NCAP); \
    const uint4* pl4_ = (const uint4*)(pairs + (size_t)(quadbase_ + g4) * NCAP); \
    float ac0 = 0.f, ac1 = 0.f, ac2 = 0.f, ac3 = 0.f; \
    int nb_ = nmax_ >> 2; \
    int t4_ = 0; \
    while (t4_ < nb_) { \
        __half2 a01 = __floats2half2_rn(0.f, 0.f); \
        __half2 a23 = __floats2half2_rn(0.f, 0.f); \
        int ce_ = (t4_ + 4 < nb_) ? t4_ + 4 : nb_; \
        for (; t4_ < ce_; ++t4_) { \
            uint4 c_ = cur_; \
            int nxt_ = (t4_ + 1 < nb_) ? t4_ + 1 : t4_; \
            cur_ = pl4_[nxt_]; \
            PROC(c_.x); PROC(c_.y); PROC(c_.z); PROC(c_.w); \
        } \
        float2 u_ = __half22float2(a01); ac0 += u_.x; ac1 += u_.y; \
        float2 v_ = __half22float2(a23); ac2 += v_.x; ac3 += v_.y; \
    } \
    nmax_cur = nmax_n_; pp_cur = pp_n_; \
    float s0_ = __shfl_xor(ac0, 16, 64), s1_ = __shfl_xor(ac1, 16, 64); \
    float s2_ = __shfl_xor(ac2, 16, 64), s3_ = __shfl_xor(ac3, 16, 64); \
    bool ge1_ = (g4 & 1) == 0; \
    float n0_ = ge1_ ? ac0 : s1_, n1_ = ge1_ ? s0_ : ac1; \
    float n2_ = ge1_ ? ac2 : s3_, n3_ = ge1_ ? s2_ : ac3; \
    s0_ = __shfl_xor(n0_, 32, 64); s1_ = __shfl_xor(n1_, 32, 64); \
    s2_ = __shfl_xor(n2_, 32, 64); s3_ = __shfl_xor(n3_, 32, 64); \
    bool ge2_ = (g4 & 2) == 0; \
    DEST = make_float4(ge2_ ? n0_ : s2_, ge2_ ? n1_ : s3_, \
                       ge2_ ? s0_ : n2_, ge2_ ? s1_ : n3_); }

__global__ __launch_bounds__(NTHREADS, 4)
void k_main(const float* __restrict__ b1, const float* __restrict__ b2,
            const float* __restrict__ s1, const float* __restrict__ s2,
            const int* __restrict__ cnt, const uint32_t* __restrict__ pairs,
            float* __restrict__ out) {
    __shared__ __align__(16) char xsh[131200];   // x2 (513 rows incl zero) + x1 (512)
    int bx = blockIdx.x;                   // 0..63 row-block
    int gy = blockIdx.y;                   // 0..3
    int r_base = bx * ROWS;
    int b = r_base >> 9;
    int w0 = r_base & (CBP_W - 1);
    int tid = threadIdx.x;

    // stage sign-folded f16, transposed [c][r]; x2 at 0, x1 at X1OFF
    for (int u = tid; u < CBP_C * 8; u += NTHREADS) {
        int c = u >> 3;
        int r8 = (u & 7) << 3;
        size_t g = ((size_t)(b * CBP_C + c)) * CBP_W + w0 + r8;
        float4 u0 = *(const float4*)(b1 + g), u1 = *(const float4*)(b1 + g + 4);
        float4 v0 = *(const float4*)(b2 + g), v1 = *(const float4*)(b2 + g + 4);
        float sa = s1[c], sb = s2[c];
        union { __half2 h2[4]; uint4 q; } A, Bv;
        A.h2[0] = __floats2half2_rn(u0.x * sa, u0.y * sa);
        A.h2[1] = __floats2half2_rn(u0.z * sa, u0.w * sa);
        A.h2[2] = __floats2half2_rn(u1.x * sa, u1.y * sa);
        A.h2[3] = __floats2half2_rn(u1.z * sa, u1.w * sa);
        Bv.h2[0] = __floats2half2_rn(v0.x * sb, v0.y * sb);
        Bv.h2[1] = __floats2half2_rn(v0.z * sb, v0.w * sb);
        Bv.h2[2] = __floats2half2_rn(v1.x * sb, v1.y * sb);
        Bv.h2[3] = __floats2half2_rn(v1.z * sb, v1.w * sb);
        *(uint4*)(xsh + X1OFF + (c << 7) + (r8 << 1)) = A.q;
        *(uint4*)(xsh + (c << 7) + (r8 << 1)) = Bv.q;
    }
    if (tid < 8) *(uint4*)(xsh + 65536 + tid * 16) = make_uint4(0, 0, 0, 0);
    __syncthreads();

    int wv = tid >> 6;                     // 0..15
    int lane = tid & 63;
    int g4 = lane >> 4;                    // quarter: d within quad
    int l = lane & 15;                     // rows 4l..4l+3
    uint32_t baseA = (uint32_t)(X1OFF + (l << 3));
    uint32_t baseB = (uint32_t)(l << 3);
    int dbase = gy * (CBP_D / NSPLIT) + wv * 128;   // wave owns 128 contiguous d's

    // cross-quad pipeline: preloaded count + first uint4 of the upcoming quad
    int nmax_cur = __builtin_amdgcn_readfirstlane(cnt[dbase]);
    uint4 pp_cur = *(const uint4*)(pairs + (size_t)(dbase + g4) * NCAP);

    // lane stores row r_base + 4l + g4, 16 consecutive d (64 B) per burst
    float* obase = out + (size_t)(r_base + (l << 2) + g4) * CBP_D + dbase;

    for (int qq = 0; qq < 8; ++qq) {
        float4 B0, B1, B2, B3;
        QUAD(0, B0); QUAD(1, B1); QUAD(2, B2); QUAD(3, B3);
        float* o_ = obase + (qq << 4);
        *(float4*)(o_)      = B0;
        *(float4*)(o_ + 4)  = B1;
        *(float4*)(o_ + 8)  = B2;
        *(float4*)(o_ + 12) = B3;
    }
}

// ================= launch =================

extern "C" void kernel_launch(void* const* d_in, const int* in_sizes, int n_in,
                              void* d_out, int out_size, void* d_ws, size_t ws_size,
                              hipStream_t stream) {
    const float* b1 = (const float*)d_in[0];
    const float* b2 = (const float*)d_in[1];
    const int*   h1 = (const int*)d_in[2];
    const float* s1 = (const float*)d_in[3];
    const int*   h2 = (const int*)d_in[4];
    const float* s2 = (const float*)d_in[5];
    float* out = (float*)d_out;

    int* cnt = (int*)d_ws;                            // 8192 (+8 pad)
    uint32_t* pairs = (uint32_t*)(cnt + 8192 + 8);    // 8192*NCAP u32 (~2.36 MB)

    pB_fill<<<128, 512, 0, stream>>>(h1, h2, cnt, pairs);

    dim3 g(CBP_W * 8 / ROWS, NSPLIT);     // (64, 4)
    k_main<<<g, NTHREADS, 0, stream>>>(b1, b2, s1, s2, cnt, pairs, out);
}